// Round 10
// baseline (64.574 us; speedup 1.0000x reference)
//
#include <hip/hip_runtime.h>
#include <stdint.h>

#define EE 1024
#define SS 512
#define NBATCH 16
#define PP 96
#define NROWS (NBATCH * SS)   // 8192
#define NJ (PP * 4)           // 384
#define EPS 1e-8f

typedef __attribute__((ext_vector_type(8))) short bf16x8;
typedef __attribute__((ext_vector_type(4))) float f32x4;

// round-to-nearest-even f32 -> bf16 bits
__device__ __forceinline__ ushort f2bf(float f) {
    uint32_t u = __float_as_uint(f);
    u += 0x7fffu + ((u >> 16) & 1u);
    return (ushort)(u >> 16);
}

__device__ __forceinline__ void gload16(const void* g, void* l) {
    __builtin_amdgcn_global_load_lds(
        (const __attribute__((address_space(1))) uint32_t*)g,
        (__attribute__((address_space(3))) uint32_t*)l, 16, 0, 0);
}

// ---- fused convert: emb (wave-per-row, 4xfloat4/lane) + proto; zeros cls ----
__global__ __launch_bounds__(256) void conv_kernel(const float* __restrict__ emb,
                                                   const float* __restrict__ proto,
                                                   ushort* __restrict__ ebf,
                                                   ushort* __restrict__ pbf,
                                                   float* __restrict__ rn2,
                                                   float* __restrict__ pn,
                                                   float* __restrict__ cls) {
    int b = blockIdx.x, t = threadIdx.x;
    if (b < NROWS / 4) {
        int r = b * 4 + (t >> 6);
        int l = t & 63;
        const float4* src = (const float4*)(emb + (size_t)r * EE);
        ushort4* dst = (ushort4*)(ebf + (size_t)r * EE);
        float s = 0.f;
#pragma unroll
        for (int i = 0; i < 4; i++) {
            float4 v = src[l + 64 * i];
            dst[l + 64 * i] = make_ushort4(f2bf(v.x), f2bf(v.y), f2bf(v.z), f2bf(v.w));
            s += v.x * v.x + v.y * v.y + v.z * v.z + v.w * v.w;
        }
#pragma unroll
        for (int off = 32; off; off >>= 1) s += __shfl_down(s, off);
        if (l == 0) rn2[r] = s;
    } else {
        int p = b - NROWS / 4;
        if (p == 0 && t < NBATCH * 2) cls[t] = 0.f;   // zero FC accumulators
        const float4* src = (const float4*)(proto + (size_t)p * 4096);
        ushort4* dst = (ushort4*)(pbf + (size_t)p * 4096);
        float s = 0.f;
#pragma unroll
        for (int i = 0; i < 4; i++) {
            float4 v = src[t + 256 * i];
            dst[t + 256 * i] = make_ushort4(f2bf(v.x), f2bf(v.y), f2bf(v.z), f2bf(v.w));
            s += v.x * v.x + v.y * v.y + v.z * v.z + v.w * v.w;
        }
#pragma unroll
        for (int off = 32; off; off >>= 1) s += __shfl_down(s, off);
        __shared__ float red[4];
        if ((t & 63) == 0) red[t >> 6] = s;
        __syncthreads();
        if (t == 0) pn[p] = sqrtf(red[0] + red[1] + red[2] + red[3]);
    }
}

// ---- strip GEMM: block = 32 A-rows x ALL 384 B-rows, K=1024, dbuf GBK=32 ----
// Rt[j][r] = sum_k A[r,k]*B[j,k].  Grid = 256 blocks x 512 threads.
#define BROWS 32
#define GBK 32
#define NKT (EE / GBK)       // 32
#define BCH (NJ * GBK / 8)   // 1536 B-chunks of 16B per K-tile
#define ACH (BROWS * GBK / 8) // 128 A-chunks

__global__ __launch_bounds__(512, 2) void gemm_kernel(const ushort* __restrict__ A,
                                                      const ushort* __restrict__ B,
                                                      float* __restrict__ Rt) {
    __shared__ ushort As[2][BROWS * GBK];   // 2 x 2 KB
    __shared__ ushort Bs[2][NJ * GBK];      // 2 x 24 KB
    int r0 = blockIdx.x * BROWS;
    int t = threadIdx.x;      // 0..511
    int lane = t & 63;
    int w = t >> 6;           // 0..7
    int fr = lane & 15;
    int kc = lane >> 4;       // 0..3

    // staging maps (16B chunks): LDS chunk c -> row=c>>2, cc=c&3,
    // global chunk gc = cc ^ (row&3)  (involution; read side mirrors it)
    int cB0 = t;            // + 512, +1024
    int rB0 = cB0 >> 2;     int gB0 = (cB0 & 3) ^ (rB0 & 3);
    int cB1 = t + 512;      int rB1 = cB1 >> 2;  int gB1 = (cB1 & 3) ^ (rB1 & 3);
    int cB2 = t + 1024;     int rB2 = cB2 >> 2;  int gB2 = (cB2 & 3) ^ (rB2 & 3);
    int rA = t >> 2;        int gA = (t & 3) ^ (rA & 3);
    const ushort* gb0 = B + (size_t)rB0 * EE + gB0 * 8;
    const ushort* gb1 = B + (size_t)rB1 * EE + gB1 * 8;
    const ushort* gb2 = B + (size_t)rB2 * EE + gB2 * 8;
    const ushort* ga = A + (size_t)(r0 + rA) * EE + gA * 8;

    f32x4 acc[2][3] = {};

    // prologue: stage K-tile 0 into buffer 0
    gload16(gb0, &Bs[0][cB0 * 8]);
    gload16(gb1, &Bs[0][cB1 * 8]);
    gload16(gb2, &Bs[0][cB2 * 8]);
    if (t < ACH) gload16(ga, &As[0][t * 8]);
    __syncthreads();

#pragma unroll 4
    for (int tt = 0; tt < NKT; ++tt) {
        int cur = tt & 1;
        if (tt + 1 < NKT) {
            int k0 = (tt + 1) * GBK;
            int nb = cur ^ 1;
            gload16(gb0 + k0, &Bs[nb][cB0 * 8]);
            gload16(gb1 + k0, &Bs[nb][cB1 * 8]);
            gload16(gb2 + k0, &Bs[nb][cB2 * 8]);
            if (t < ACH) gload16(ga + k0, &As[nb][t * 8]);
        }
        const ushort* as = As[cur];
        const ushort* bs = Bs[cur];
        bf16x8 af[2], bf[3];
#pragma unroll
        for (int m = 0; m < 2; m++) {
            int row = m * 16 + fr;
            af[m] = *(const bf16x8*)(as + row * GBK + (kc ^ (row & 3)) * 8);
        }
#pragma unroll
        for (int n = 0; n < 3; n++) {
            int row = w * 48 + n * 16 + fr;
            bf[n] = *(const bf16x8*)(bs + row * GBK + (kc ^ (row & 3)) * 8);
        }
#pragma unroll
        for (int m = 0; m < 2; m++)
#pragma unroll
            for (int n = 0; n < 3; n++)
                acc[m][n] = __builtin_amdgcn_mfma_f32_16x16x32_bf16(af[m], bf[n], acc[m][n], 0, 0, 0);
        __syncthreads();
    }

    int rloc = r0 + (lane >> 4) * 4;
#pragma unroll
    for (int m = 0; m < 2; m++)
#pragma unroll
        for (int n = 0; n < 3; n++) {
            int jloc = w * 48 + n * 16 + fr;
            *(f32x4*)(Rt + (size_t)jloc * NROWS + rloc + m * 16) = acc[m][n];
        }
}

// ---- combine: coalesced stage -> LDS gather; min-pool of -cos; fused FC ----
#define CPAD 520

__global__ __launch_bounds__(256) void combine_kernel(const float* __restrict__ Rt,
                                                      const float* __restrict__ rn2,
                                                      const float* __restrict__ pn,
                                                      const float* __restrict__ fcw,
                                                      float* __restrict__ out,
                                                      float* __restrict__ cls) {
    __shared__ float sR[4][4][CPAD];   // [wave][j][col]
    __shared__ float sN2[512];
    int b = blockIdx.x;
    int n = b & 15;
    int pg = b >> 4;
    int t = threadIdx.x;
    int w = t >> 6, l = t & 63;
    int p = pg * 4 + w;

    sN2[t] = rn2[n * SS + t];
    sN2[t + 256] = rn2[n * SS + t + 256];

#pragma unroll
    for (int j = 0; j < 4; j++) {
        const float4* rp = (const float4*)(Rt + (size_t)(4 * p + j) * NROWS + n * SS);
        *(float4*)&sR[w][j][4 * l] = rp[l];
        *(float4*)&sR[w][j][256 + 4 * l] = rp[l + 64];
    }
    __syncthreads();

    int d = (p >> 5) + 1;
    int H = SS - 3 * d;
    int Hd = H - d;
    float pnv = fmaxf(pn[p], EPS);
    float best = -3.4e38f;
    for (int h = l; h < H; h += 64) {
        float dot = 0.f, x2 = 0.f;
#pragma unroll
        for (int j = 0; j < 4; j++) {
            int q = h * 4 + j;
            int k = (q >= H) + (q >= 2 * H) + (q >= 3 * H);
            int s = q - k * Hd;
            dot += sR[w][j][s];
            x2 += sN2[s];
        }
        float xn = fmaxf(sqrtf(x2), EPS);
        best = fmaxf(best, dot / (xn * pnv));
    }
#pragma unroll
    for (int off = 32; off; off >>= 1) best = fmaxf(best, __shfl_down(best, off));
    if (l == 0) {
        float pdv = -best;
        out[n * PP + p] = pdv;
        atomicAdd(&cls[n * 2 + 0], pdv * fcw[p]);
        atomicAdd(&cls[n * 2 + 1], pdv * fcw[PP + p]);
    }
}

extern "C" void kernel_launch(void* const* d_in, const int* in_sizes, int n_in,
                              void* d_out, int out_size, void* d_ws, size_t ws_size,
                              hipStream_t stream) {
    const float* emb = (const float*)d_in[0];     // (16,512,1024) f32
    const float* proto = (const float*)d_in[2];   // (96,1024,4) f32 flat = (384,1024)
    const float* fcw = (const float*)d_in[3];     // (2,96)
    float* out = (float*)d_out;
    float* cls = out + NBATCH * PP;

    uint8_t* ws = (uint8_t*)d_ws;
    ushort* ebf = (ushort*)ws;                                   // 16 MB
    ushort* pbf = (ushort*)(ws + (size_t)NROWS * EE * 2);        // 0.75 MB
    float* rn2 = (float*)(ws + (size_t)NROWS * EE * 2 + (size_t)NJ * EE * 2);
    float* pn = rn2 + NROWS;
    float* Rt = pn + 128;  // 16B-aligned; single plane NJ*NROWS f32

    conv_kernel<<<NROWS / 4 + PP, 256, 0, stream>>>(emb, proto, ebf, pbf, rn2, pn, cls);
    gemm_kernel<<<NROWS / BROWS, 512, 0, stream>>>(ebf, pbf, Rt);
    combine_kernel<<<NBATCH * PP / 4, 256, 0, stream>>>(Rt, rn2, pn, fcw, out, cls);
}